// Round 13
// baseline (14975.093 us; speedup 1.0000x reference)
//
#include <hip/hip_runtime.h>
#include <hip/hip_bf16.h>

#define T_STEPS 1024
#define NWG     32

typedef __attribute__((ext_vector_type(8))) short          bf16x8;
typedef __attribute__((ext_vector_type(4))) float          f32x4;
typedef __attribute__((ext_vector_type(8))) unsigned short u16x8;
typedef unsigned long long ull;

static __device__ __forceinline__ unsigned short f2bf_bits(float f) {
    union { __hip_bfloat16 h; unsigned short u; } cv;
    cv.h = __float2bfloat16(f);
    return cv.u;
}

// ---------------------------------------------------------------------------
// P1: fold ln_g into weights, cast bf16, MFMA B-frag order.
// Chunk blk = g*2 + part (g 0..31, part 0=x rows, 1=h rows), 32768 u16 each:
//   offset ((q*16+ks)*64+lane)*8+e ; value = Wq[k*512 + g*16 + (lane&15)]*ln_g[k]
//   with k = part*512 + ks*32 + (lane>>4)*8 + e,  gate col n = q*512+g*16+(lane&15)
// ---------------------------------------------------------------------------
__global__ __launch_bounds__(256) void pack_weights(
    const float* __restrict__ Wf, const float* __restrict__ Wi,
    const float* __restrict__ Wg, const float* __restrict__ Wo,
    const float* __restrict__ ln_g, __hip_bfloat16* __restrict__ pack)
{
    __shared__ float tile[512 * 16];
    const int blk = blockIdx.x;
    const int g = blk >> 1, part = blk & 1;
    const int tid = threadIdx.x;
    unsigned short* outp = (unsigned short*)pack + (size_t)blk * 32768;

    for (int q = 0; q < 4; ++q) {
        const float* W = (q == 0) ? Wf : ((q == 1) ? Wi : ((q == 2) ? Wg : Wo));
        for (int idx = tid; idx < 512 * 16; idx += 256) {
            int kl = idx >> 4, c = idx & 15;
            int k = part * 512 + kl;
            tile[idx] = W[k * 512 + g * 16 + c] * ln_g[k];
        }
        __syncthreads();
        for (int s = tid; s < 8192; s += 256) {
            int ks = s >> 9, lane = (s >> 3) & 63, e = s & 7;
            int kl = ks * 32 + ((lane >> 4) << 3) + e, c = lane & 15;
            outp[(((q * 16 + ks) << 6) + lane) * 8 + e] = f2bf_bits(tile[kl * 16 + c]);
        }
        __syncthreads();
    }
}

// ---------------------------------------------------------------------------
// P2: S[n] = sum_k ln_g[k]*W[k,n],  C[n] = sum_k ln_b[k]*W[k,n] + bias[n]
// ---------------------------------------------------------------------------
__global__ __launch_bounds__(256) void compute_sc(
    const float* __restrict__ Wf, const float* __restrict__ Wi,
    const float* __restrict__ Wg, const float* __restrict__ Wo,
    const float* __restrict__ bf_, const float* __restrict__ bi_,
    const float* __restrict__ bg_, const float* __restrict__ bo_,
    const float* __restrict__ ln_g, const float* __restrict__ ln_b,
    float* __restrict__ S, float* __restrict__ C)
{
    int n = blockIdx.x * 256 + threadIdx.x;
    int q = n >> 9, j = n & 511;
    const float* W = (q == 0) ? Wf : ((q == 1) ? Wi : ((q == 2) ? Wg : Wo));
    const float* bb = (q == 0) ? bf_ : ((q == 1) ? bi_ : ((q == 2) ? bg_ : bo_));
    float accS = 0.f, accC = 0.f;
    for (int k = 0; k < 1024; ++k) {
        float w = W[k * 512 + j];
        accS += ln_g[k] * w;
        accC += ln_b[k] * w;
    }
    S[n] = accS;
    C[n] = accC + bb[j];
}

// ---------------------------------------------------------------------------
// P3: x -> bf16 copy + per-row sum / sumsq (fp32). One wave per (t,b) row.
// ---------------------------------------------------------------------------
__global__ __launch_bounds__(256) void prep_x(
    const float* __restrict__ x, __hip_bfloat16* __restrict__ xb,
    float* __restrict__ sx, float* __restrict__ sq)
{
    const int wave = threadIdx.x >> 6, lane = threadIdx.x & 63;
    const long row = (long)blockIdx.x * 4 + wave;
    const float* src = x + row * 512 + lane * 8;
    float4 a = *(const float4*)src;
    float4 b = *(const float4*)(src + 4);
    float vals[8] = {a.x, a.y, a.z, a.w, b.x, b.y, b.z, b.w};
    u16x8 o;
    float s = 0.f, qq = 0.f;
#pragma unroll
    for (int e = 0; e < 8; ++e) {
        s += vals[e];
        qq += vals[e] * vals[e];
        o[e] = f2bf_bits(vals[e]);
    }
    *(u16x8*)((unsigned short*)xb + row * 512 + lane * 8) = o;
#pragma unroll
    for (int d = 1; d < 64; d <<= 1) {
        s  += __shfl_xor(s, d);
        qq += __shfl_xor(qq, d);
    }
    if (lane == 0) { sx[row] = s; sq[row] = qq; }
}

// ---------------------------------------------------------------------------
// Main persistent kernel: 32 WGs x 512 thr. WG g owns h-cols [16g,16g+16)
// (64 gate cols). Wave w: m = w>>1 (16-row tile), kh = w&1 (K half).
// Wh register-resident (128 VGPR/wave); Wx streamed from L2 in shadow zX GEMM
// (prefetched A-frags). LN stats consumer-side from loaded h words (R6).
// Sync: R6's agent-scope per-WG flags; consumer wave kh polls its 16 producer
// WGs only (lane l -> flags of WG kh*16+(l&15)). Publish = agent stores +
// vmcnt(0) + barrier + tid0 flag. z-partials exchanged via LDS (97 KB).
// Gate thread: b = tid>>3, cols g*16 + (tid&7)*2 .. +2.
// ---------------------------------------------------------------------------
__global__ __launch_bounds__(512, 2) void qlstm_main(
    const float* __restrict__ x,
    const __hip_bfloat16* __restrict__ pack,
    const float* __restrict__ Sarr, const float* __restrict__ Carr,
    const __hip_bfloat16* __restrict__ xb,
    const float* __restrict__ sx, const float* __restrict__ sq,
    unsigned short* __restrict__ hxb,   // [2][64][512] bf16 (zeroed)
    unsigned int* __restrict__ flags,   // [32 WG][16 u32] (zeroed)
    float* __restrict__ out)            // stacked | hx | cx (fp32)
{
    const int g = blockIdx.x;
    const int tid = threadIdx.x;
    const int wave = tid >> 6, lane = tid & 63;
    const int m = wave >> 1, kh = wave & 1;
    const int b = tid >> 3, c2 = (tid & 7) * 2;

    __shared__ float zX[2][2][4][64][16];   // [parity][kh][q][row][col] 64 KB
    __shared__ float zH[2][4][64][16];      // [kh][q][row][col]         32 KB
    __shared__ float rsS[2][64], rsQ[2][64];

    // persistent h-part B-frags: [q 4][i 8] = 32 frags = 128 VGPR
    bf16x8 Bh[4][8];
    {
        const bf16x8* ph = (const bf16x8*)pack + (size_t)(g * 2 + 1) * 4096;
#pragma unroll
        for (int q = 0; q < 4; ++q)
#pragma unroll
            for (int i = 0; i < 8; ++i)
                Bh[q][i] = ph[(q * 16 + kh * 8 + i) * 64 + lane];
    }
    const bf16x8* pxw = (const bf16x8*)pack + (size_t)(g * 2 + 0) * 4096;

    const int arow = m * 16 + (lane & 15);
    const int a8   = (lane >> 4) * 8;
    const int r4   = (lane >> 4) * 4, c0 = lane & 15;

    // loop-invariant folded LN coefficients for this gate thread
    float Sv[4][2], Cv[4][2];
#pragma unroll
    for (int q = 0; q < 4; ++q)
#pragma unroll
        for (int d = 0; d < 2; ++d) {
            int n = q * 512 + g * 16 + c2 + d;
            Sv[q][d] = Sarr[n];
            Cv[q][d] = Carr[n];
        }

    float cx[2] = {0.f, 0.f};
    bf16x8 afr[8];

    auto LOADA = [&](int tt) {
        const bf16x8* Ap = (const bf16x8*)(xb + (size_t)tt * 32768
                                           + arow * 512 + kh * 256 + a8);
#pragma unroll
        for (int i = 0; i < 8; ++i) afr[i] = Ap[i * 4];
    };
    auto XSHADOW = [&](int pn) {
        f32x4 za[4];
#pragma unroll
        for (int q = 0; q < 4; ++q) za[q] = (f32x4){0.f, 0.f, 0.f, 0.f};
#pragma unroll
        for (int i = 0; i < 8; ++i) {
            bf16x8 a = afr[i];
#pragma unroll
            for (int q = 0; q < 4; ++q)
                za[q] = __builtin_amdgcn_mfma_f32_16x16x32_bf16(
                    a, pxw[(q * 16 + kh * 8 + i) * 64 + lane], za[q], 0, 0, 0);
        }
#pragma unroll
        for (int q = 0; q < 4; ++q)
#pragma unroll
            for (int r = 0; r < 4; ++r)
                zX[pn][kh][q][m * 16 + r4 + r][c0] = za[q][r];
    };

    LOADA(0);
    XSHADOW(0);
    LOADA(1);
    __syncthreads();

#pragma unroll 1
    for (int t = 0; t < T_STEPS; ++t) {
        const int p = t & 1;

        // gate-side prefetch (recurrence-independent)
        const float* xp = x + (size_t)t * 32768 + b * 512 + g * 16 + c2;
        float xr0 = __builtin_nontemporal_load(xp);
        float xr1 = __builtin_nontemporal_load(xp + 1);
        float sxv = sx[t * 64 + b];
        float sqv = sq[t * 64 + b];

        // ---- spin: poll only the 16 producer WGs of this kh half ----
        if (t) {
            const unsigned int* fp_ = flags + (kh * 16 + (lane & 15)) * 16;
            int slp = 0;
            for (;;) {
                unsigned f = __hip_atomic_load(fp_, __ATOMIC_RELAXED,
                                               __HIP_MEMORY_SCOPE_AGENT);
                if (__all((int)f >= t)) break;
                if      (slp == 0) __builtin_amdgcn_s_sleep(1);
                else if (slp == 1) __builtin_amdgcn_s_sleep(2);
                else               __builtin_amdgcn_s_sleep(4);
                if (slp < 2) ++slp;
            }
            asm volatile("" ::: "memory");
        }

        // ---- coherent h A-frag loads (16 x 8B per lane) ----
        ull w0[8], w1[8];
        {
            const ull* hp = (const ull*)hxb + (size_t)p * 8192;
            const int eb = (arow * 512 + kh * 256 + a8) >> 2;
#pragma unroll
            for (int i = 0; i < 8; ++i) {
                w0[i] = __hip_atomic_load(hp + eb + i * 8, __ATOMIC_RELAXED,
                                          __HIP_MEMORY_SCOPE_AGENT);
                w1[i] = __hip_atomic_load(hp + eb + i * 8 + 1, __ATOMIC_RELAXED,
                                          __HIP_MEMORY_SCOPE_AGENT);
            }
        }

        // ---- h-GEMM: 32 MFMA (K-half x 4 gate ntiles) ----
        f32x4 acc[4];
#pragma unroll
        for (int q = 0; q < 4; ++q) acc[q] = (f32x4){0.f, 0.f, 0.f, 0.f};
#pragma unroll
        for (int i = 0; i < 8; ++i) {
            union { ull u[2]; bf16x8 v; } cv;
            cv.u[0] = w0[i]; cv.u[1] = w1[i];
#pragma unroll
            for (int q = 0; q < 4; ++q)
                acc[q] = __builtin_amdgcn_mfma_f32_16x16x32_bf16(
                    cv.v, Bh[q][i], acc[q], 0, 0, 0);
        }

        // ---- local LN stats from loaded h words ----
        {
            float s = 0.f, qq = 0.f;
#pragma unroll
            for (int i = 0; i < 8; ++i) {
                unsigned uu[4] = { (unsigned)w0[i], (unsigned)(w0[i] >> 32),
                                   (unsigned)w1[i], (unsigned)(w1[i] >> 32) };
#pragma unroll
                for (int j = 0; j < 4; ++j) {
                    float f0 = __uint_as_float(uu[j] << 16);
                    float f1 = __uint_as_float(uu[j] & 0xffff0000u);
                    s += f0 + f1;
                    qq = fmaf(f0, f0, fmaf(f1, f1, qq));
                }
            }
            s += __shfl_xor(s, 16); qq += __shfl_xor(qq, 16);
            s += __shfl_xor(s, 32); qq += __shfl_xor(qq, 32);
            if (lane < 16) { rsS[kh][m * 16 + lane] = s; rsQ[kh][m * 16 + lane] = qq; }
        }

        // ---- zH dump ----
#pragma unroll
        for (int q = 0; q < 4; ++q)
#pragma unroll
            for (int r = 0; r < 4; ++r)
                zH[kh][q][m * 16 + r4 + r][c0] = acc[q][r];

        __syncthreads();   // (A)

        // ---- gates: thread owns (b, cols g*16+c2, +1) ----
        float hval[2];
        {
            float mu = (sxv + rsS[0][b] + rsS[1][b]) * (1.f / 1024.f);
            float var = (sqv + rsQ[0][b] + rsQ[1][b]) * (1.f / 1024.f) - mu * mu;
            float rs = rsqrtf(var + 1e-5f);
#pragma unroll
            for (int d = 0; d < 2; ++d) {
                int cl = c2 + d;
                float z0 = zX[p][0][0][b][cl] + zX[p][1][0][b][cl]
                         + zH[0][0][b][cl]    + zH[1][0][b][cl];
                float z1 = zX[p][0][1][b][cl] + zX[p][1][1][b][cl]
                         + zH[0][1][b][cl]    + zH[1][1][b][cl];
                float z2 = zX[p][0][2][b][cl] + zX[p][1][2][b][cl]
                         + zH[0][2][b][cl]    + zH[1][2][b][cl];
                float z3 = zX[p][0][3][b][cl] + zX[p][1][3][b][cl]
                         + zH[0][3][b][cl]    + zH[1][3][b][cl];
                float zf = rs * (z0 - mu * Sv[0][d]) + Cv[0][d];
                float zi = rs * (z1 - mu * Sv[1][d]) + Cv[1][d];
                float zg = rs * (z2 - mu * Sv[2][d]) + Cv[2][d];
                float zo = rs * (z3 - mu * Sv[3][d]) + Cv[3][d];
                float fg = 1.f / (1.f + __expf(-zf));
                float ig = 1.f / (1.f + __expf(-zi));
                float gg = 2.f / (1.f + __expf(-2.f * zg)) - 1.f;
                float og = 1.f / (1.f + __expf(-zo));
                cx[d] = fg * cx[d] + ig * gg;
                float th = 2.f / (1.f + __expf(-2.f * cx[d])) - 1.f;
                hval[d] = og * th + ((d == 0) ? xr0 : xr1);
            }
        }

        // ---- publish h (one 4B agent store per thread) + drain ----
        if (t + 1 < T_STEPS) {
            unsigned hb = (unsigned)f2bf_bits(hval[0]) |
                          ((unsigned)f2bf_bits(hval[1]) << 16);
            unsigned* hd = (unsigned*)(hxb + (size_t)(p ^ 1) * 32768
                                       + b * 512 + g * 16 + c2);
            __hip_atomic_store(hd, hb, __ATOMIC_RELAXED, __HIP_MEMORY_SCOPE_AGENT);
            asm volatile("s_waitcnt vmcnt(0)" ::: "memory");
        }
        __syncthreads();   // (B)
        if (t + 1 < T_STEPS && tid == 0) {
            __hip_atomic_store(flags + g * 16, (unsigned)(t + 1),
                               __ATOMIC_RELAXED, __HIP_MEMORY_SCOPE_AGENT);
        }

        // ---- shadow: out writes + zX(t+1) + prefetch ----
        float* ob = out + (size_t)t * 32768 + b * 512 + g * 16 + c2;
        __builtin_nontemporal_store(hval[0], ob);
        __builtin_nontemporal_store(hval[1], ob + 1);
        if (t == T_STEPS - 1) {
            size_t b1 = (size_t)T_STEPS * 32768 + b * 512 + g * 16 + c2;
            out[b1] = hval[0]; out[b1 + 1] = hval[1];
            out[b1 + 32768] = cx[0]; out[b1 + 32769] = cx[1];
        }
        if (t + 1 < T_STEPS) {
            XSHADOW((t + 1) & 1);
            if (t + 2 < T_STEPS) LOADA(t + 2);
        }
    }
}

// ---------------------------------------------------------------------------
extern "C" void kernel_launch(void* const* d_in, const int* in_sizes, int n_in,
                              void* d_out, int out_size, void* d_ws, size_t ws_size,
                              hipStream_t stream)
{
    const float* x    = (const float*)d_in[0];
    const float* ln_g = (const float*)d_in[1];
    const float* ln_b = (const float*)d_in[2];
    const float* Wf   = (const float*)d_in[3];
    const float* bf_  = (const float*)d_in[4];
    const float* Wi   = (const float*)d_in[5];
    const float* bi_  = (const float*)d_in[6];
    const float* Wg   = (const float*)d_in[7];
    const float* bg_  = (const float*)d_in[8];
    const float* Wo   = (const float*)d_in[9];
    const float* bo_  = (const float*)d_in[10];

    char* ws = (char*)d_ws;
    size_t off = 0;
    auto take = [&](size_t bytes) -> char* {
        char* p = ws + off;
        off += (bytes + 255) & ~(size_t)255;
        return p;
    };
    __hip_bfloat16* pack = (__hip_bfloat16*)take((size_t)64 * 32768 * 2);   // 4 MB
    float* S             = (float*)take(2048 * 4);
    float* C             = (float*)take(2048 * 4);
    __hip_bfloat16* xb   = (__hip_bfloat16*)take((size_t)33554432 * 2);     // 64 MB
    float* sx            = (float*)take(65536 * 4);
    float* sq            = (float*)take(65536 * 4);
    char* ctrl = ws + off;
    unsigned short* hxb  = (unsigned short*)take((size_t)2 * 64 * 512 * 2); // 128 KB
    unsigned int* flags  = (unsigned int*)take(32 * 64);                    // 2 KB
    size_t ctrl_bytes = (size_t)((ws + off) - ctrl);

    hipMemsetAsync(ctrl, 0, ctrl_bytes, stream);
    pack_weights<<<dim3(64), dim3(256), 0, stream>>>(Wf, Wi, Wg, Wo, ln_g, pack);
    compute_sc<<<dim3(8), dim3(256), 0, stream>>>(Wf, Wi, Wg, Wo, bf_, bi_, bg_, bo_,
                                                  ln_g, ln_b, S, C);
    prep_x<<<dim3(16384), dim3(256), 0, stream>>>(x, xb, sx, sq);
    qlstm_main<<<dim3(NWG), dim3(512), 0, stream>>>(x, pack, S, C, xb, sx, sq,
                                                    hxb, flags, (float*)d_out);
}

// Round 15
// 6032.706 us; speedup vs baseline: 2.4823x; 2.4823x over previous
//
#include <hip/hip_runtime.h>
#include <hip/hip_bf16.h>

#define T_STEPS 1024
#define NWG     64

typedef __attribute__((ext_vector_type(8))) short          bf16x8;
typedef __attribute__((ext_vector_type(4))) float          f32x4;
typedef __attribute__((ext_vector_type(8))) unsigned short u16x8;
typedef unsigned long long ull;

static __device__ __forceinline__ unsigned short f2bf_bits(float f) {
    union { __hip_bfloat16 h; unsigned short u; } cv;
    cv.h = __float2bfloat16(f);
    return cv.u;
}

// ---------------------------------------------------------------------------
// P1: fold ln_g into weights, cast bf16, emit in MFMA B-fragment order.
// Chunk layout: [g][part][tn][kstep][lane][e]
//   k  = part*512 + kstep*32 + (lane>>4)*8 + e
//   c  = tn*16 + (lane&15);  n = (c>>3)*512 + g*8 + (c&7)
// ---------------------------------------------------------------------------
__global__ __launch_bounds__(256) void pack_weights(
    const float* __restrict__ Wf, const float* __restrict__ Wi,
    const float* __restrict__ Wg, const float* __restrict__ Wo,
    const float* __restrict__ ln_g, __hip_bfloat16* __restrict__ pack)
{
    __shared__ unsigned short tile[512 * 32];   // [k_local][c]
    const int blk = blockIdx.x;
    const int g = blk >> 1, part = blk & 1;
    const int tid = threadIdx.x;

    for (int idx = tid; idx < 512 * 32; idx += 256) {
        int kl = idx >> 5, c = idx & 31;
        int q = c >> 3, jl = c & 7;
        int k = part * 512 + kl;
        const float* W = (q == 0) ? Wf : ((q == 1) ? Wi : ((q == 2) ? Wg : Wo));
        float v = W[k * 512 + g * 8 + jl] * ln_g[k];
        tile[kl * 32 + c] = f2bf_bits(v);
    }
    __syncthreads();

    unsigned short* out = (unsigned short*)(pack + (size_t)blk * 16384);
    for (int s = tid; s < 2048; s += 256) {        // slot = tn*1024 + ks*64 + l
        int tn = s >> 10, ks = (s >> 6) & 15, l = s & 63;
        u16x8 v;
#pragma unroll
        for (int e = 0; e < 8; ++e) {
            int klocal = ks * 32 + ((l >> 4) * 8) + e;
            int c = tn * 16 + (l & 15);
            v[e] = tile[klocal * 32 + c];
        }
        *(u16x8*)(out + (size_t)s * 8) = v;
    }
}

// ---------------------------------------------------------------------------
// P2: S[n] = sum_k ln_g[k]*W[k,n],  C[n] = sum_k ln_b[k]*W[k,n] + bias[n]
// ---------------------------------------------------------------------------
__global__ __launch_bounds__(256) void compute_sc(
    const float* __restrict__ Wf, const float* __restrict__ Wi,
    const float* __restrict__ Wg, const float* __restrict__ Wo,
    const float* __restrict__ bf_, const float* __restrict__ bi_,
    const float* __restrict__ bg_, const float* __restrict__ bo_,
    const float* __restrict__ ln_g, const float* __restrict__ ln_b,
    float* __restrict__ S, float* __restrict__ C)
{
    int n = blockIdx.x * 256 + threadIdx.x;        // 0..2047
    int q = n >> 9, j = n & 511;
    const float* W = (q == 0) ? Wf : ((q == 1) ? Wi : ((q == 2) ? Wg : Wo));
    const float* bb = (q == 0) ? bf_ : ((q == 1) ? bi_ : ((q == 2) ? bg_ : bo_));
    float accS = 0.f, accC = 0.f;
    for (int k = 0; k < 1024; ++k) {
        float w = W[k * 512 + j];
        accS += ln_g[k] * w;
        accC += ln_b[k] * w;
    }
    S[n] = accS;
    C[n] = accC + bb[j];
}

// ---------------------------------------------------------------------------
// P3: x -> bf16 copy + per-row sum / sumsq (fp32). One wave per (t,b) row.
// ---------------------------------------------------------------------------
__global__ __launch_bounds__(256) void prep_x(
    const float* __restrict__ x, __hip_bfloat16* __restrict__ xb,
    float* __restrict__ sx, float* __restrict__ sq)
{
    const int wave = threadIdx.x >> 6, lane = threadIdx.x & 63;
    const long row = (long)blockIdx.x * 4 + wave;  // 0..65535
    const float* src = x + row * 512 + lane * 8;
    float4 a = *(const float4*)src;
    float4 b = *(const float4*)(src + 4);
    float vals[8] = {a.x, a.y, a.z, a.w, b.x, b.y, b.z, b.w};
    u16x8 o;
    float s = 0.f, qq = 0.f;
#pragma unroll
    for (int e = 0; e < 8; ++e) {
        s += vals[e];
        qq += vals[e] * vals[e];
        o[e] = f2bf_bits(vals[e]);
    }
    *(u16x8*)((unsigned short*)xb + row * 512 + lane * 8) = o;
#pragma unroll
    for (int d = 1; d < 64; d <<= 1) {
        s  += __shfl_xor(s, d);
        qq += __shfl_xor(qq, d);
    }
    if (lane == 0) { sx[row] = s; sq[row] = qq; }
}

// ---------------------------------------------------------------------------
// Main persistent kernel: 64 WGs x 512 threads — R6 structure (replay-proven
// sync: per-(WG,wave) SPACED flags, sc1 stores + vmcnt(0) + lane0 flag) with
// ONE change: producer-private h layout.
//   hxb[parity][wg][row 64][8 cols] bf16 — 1 KB/WG region, u64 view:
//     producer (b, jl in {0,4}): u64 idx = g*128 + b*2 + (jl>>2)
//     consumer kstep ks: region g' = kh*32 + ks*4 + (lane>>4),
//       hlo = [g'*128 + arow*2], hhi = [g'*128 + arow*2 + 1]
//   (col base kh*256+ks*32+(lane>>4)*8 == 8*g', so the 16B pair is exactly
//    the A-fragment word — verified against R6's row-major indexing.)
// Wave w: m = w>>1 (16-row M tile), kh = w&1 (K half).
// Thread t: b = t>>3, jl = t&7 owns gate/state element (b, 8g+jl).
// ---------------------------------------------------------------------------
__global__ __launch_bounds__(512, 2) void qlstm_main(
    const float* __restrict__ x,
    const __hip_bfloat16* __restrict__ pack,
    const float* __restrict__ Sarr, const float* __restrict__ Carr,
    const __hip_bfloat16* __restrict__ xb,
    const float* __restrict__ sx, const float* __restrict__ sq,
    unsigned short* __restrict__ hxb,   // [2][64 wg][64 row][8] bf16 (zeroed)
    unsigned int* __restrict__ flags,   // [64 WG][16 u32] = 64B/WG (zeroed)
    float* __restrict__ out)            // stacked | hx | cx (fp32)
{
    const int g = blockIdx.x;
    const int tid = threadIdx.x;
    const int wave = tid >> 6, lane = tid & 63;
    const int m = wave >> 1, kh = wave & 1;
    const int b = tid >> 3, jl = tid & 7, jg = g * 8 + jl;

    __shared__ float zXs[2][2][2112];          // [parity][kh][row*33+col]
    __shared__ float zHs[2][2112];             // [kh]
    __shared__ float rsS[64][2], rsQ[64][2];   // per-row h sum/sumsq, per kh
    __shared__ float Scol[32], Ccol[32];

    if (tid < 32) {
        int n = (tid >> 3) * 512 + g * 8 + (tid & 7);
        Scol[tid] = Sarr[n];
        Ccol[tid] = Carr[n];
    }

    // Persistent B-fragments: 4 x 8 frags x 4 VGPR = 128 regs.
    bf16x8 Bx0[8], Bx1[8], Bh0[8], Bh1[8];
    {
        const bf16x8* px = (const bf16x8*)(pack + (size_t)(g * 2 + 0) * 16384);
        const bf16x8* ph = (const bf16x8*)(pack + (size_t)(g * 2 + 1) * 16384);
#pragma unroll
        for (int i = 0; i < 8; ++i) {
            int ksp = kh * 8 + i;
            Bx0[i] = px[ksp * 64 + lane];
            Bx1[i] = px[1024 + ksp * 64 + lane];
            Bh0[i] = ph[ksp * 64 + lane];
            Bh1[i] = ph[1024 + ksp * 64 + lane];
        }
    }

    const int arow = m * 16 + (lane & 15);
    const int acol = (lane >> 4) * 8;
    const int r0 = m * 16 + (lane >> 4) * 4, c0 = lane & 15;
    float cx = 0.f;

    auto xgemm_store = [&](const bf16x8* af, int par) {
        f32x4 a0 = {0.f, 0.f, 0.f, 0.f}, a1 = {0.f, 0.f, 0.f, 0.f};
#pragma unroll
        for (int ks = 0; ks < 8; ++ks) {
            a0 = __builtin_amdgcn_mfma_f32_16x16x32_bf16(af[ks], Bx0[ks], a0, 0, 0, 0);
            a1 = __builtin_amdgcn_mfma_f32_16x16x32_bf16(af[ks], Bx1[ks], a1, 0, 0, 0);
        }
        float* zb = &zXs[par][kh][0];
#pragma unroll
        for (int r = 0; r < 4; ++r) {
            zb[(r0 + r) * 33 + c0]      = a0[r];
            zb[(r0 + r) * 33 + 16 + c0] = a1[r];
        }
    };

    // zX for t=0 (recurrence-independent)
    {
        const bf16x8* Ap = (const bf16x8*)(xb + (size_t)arow * 512 + kh * 256 + acol);
        bf16x8 af[8];
#pragma unroll
        for (int ks = 0; ks < 8; ++ks) af[ks] = Ap[ks * 4];
        xgemm_store(af, 0);
    }

    for (int t = 0; t < T_STEPS; ++t) {
        const int p = t & 1;

        // ---- recurrence-independent loads issued BEFORE the spin ----
        float xres = x[(size_t)t * 32768 + b * 512 + jg];
        float sxv = sx[t * 64 + b];
        float sqv = sq[t * 64 + b];
        bf16x8 afrN[8];                     // x A-frags for t+1
        if (t + 1 < T_STEPS) {
            const bf16x8* Ap = (const bf16x8*)(xb + (size_t)(t + 1) * 32768
                                               + arow * 512 + kh * 256 + acol);
#pragma unroll
            for (int ks = 0; ks < 8; ++ks) afrN[ks] = Ap[ks * 4];
        }

        // ---- spin (R6): lane l polls waves {2m,2m+1} of WG l, 8B load ----
        if (t) {
            const ull* fp_ = (const ull*)(flags + lane * 16 + m * 2);
            int slp = 0;
            for (;;) {
                ull v = __hip_atomic_load(fp_, __ATOMIC_RELAXED,
                                          __HIP_MEMORY_SCOPE_AGENT);
                unsigned fa = (unsigned)v, fb = (unsigned)(v >> 32);
                unsigned mn = fa < fb ? fa : fb;
                if (__all((int)mn >= t)) break;
                if      (slp == 0) __builtin_amdgcn_s_sleep(1);
                else if (slp == 1) __builtin_amdgcn_s_sleep(2);
                else if (slp == 2) __builtin_amdgcn_s_sleep(4);
                else               __builtin_amdgcn_s_sleep(8);
                if (slp < 3) ++slp;
            }
            asm volatile("" ::: "memory");
        }

        // ---- coherent h A-frag loads from producer-private regions ----
        ull hlo[8], hhi[8];
        {
            const ull* hp = (const ull*)hxb + (size_t)p * 8192;
            const int g0 = kh * 32 + (lane >> 4);
            const int rb = arow * 2;
#pragma unroll
            for (int ks = 0; ks < 8; ++ks) {
                const int idx = (g0 + ks * 4) * 128 + rb;
                hlo[ks] = __hip_atomic_load(hp + idx, __ATOMIC_RELAXED,
                                            __HIP_MEMORY_SCOPE_AGENT);
                hhi[ks] = __hip_atomic_load(hp + idx + 1, __ATOMIC_RELAXED,
                                            __HIP_MEMORY_SCOPE_AGENT);
            }
        }

        // ---- h-GEMM (critical path) ----
        {
            f32x4 h0 = {0.f, 0.f, 0.f, 0.f}, h1 = {0.f, 0.f, 0.f, 0.f};
#pragma unroll
            for (int ks = 0; ks < 8; ++ks) {
                union { ull u[2]; bf16x8 v; } cv;
                cv.u[0] = hlo[ks]; cv.u[1] = hhi[ks];
                h0 = __builtin_amdgcn_mfma_f32_16x16x32_bf16(cv.v, Bh0[ks], h0, 0, 0, 0);
                h1 = __builtin_amdgcn_mfma_f32_16x16x32_bf16(cv.v, Bh1[ks], h1, 0, 0, 0);
            }
            float* zb = &zHs[kh][0];
#pragma unroll
            for (int r = 0; r < 4; ++r) {
                zb[(r0 + r) * 33 + c0]      = h0[r];
                zb[(r0 + r) * 33 + 16 + c0] = h1[r];
            }
        }

        // ---- local LN stats from the loaded h words ----
        {
            float s = 0.f, q = 0.f;
#pragma unroll
            for (int ks = 0; ks < 8; ++ks) {
                unsigned uu[4] = { (unsigned)hlo[ks], (unsigned)(hlo[ks] >> 32),
                                   (unsigned)hhi[ks], (unsigned)(hhi[ks] >> 32) };
#pragma unroll
                for (int j = 0; j < 4; ++j) {
                    float f0 = __uint_as_float(uu[j] << 16);
                    float f1 = __uint_as_float(uu[j] & 0xffff0000u);
                    s += f0 + f1;
                    q = fmaf(f0, f0, fmaf(f1, f1, q));
                }
            }
            // lanes {l, l^16, l^32, l^48} share arow
            s += __shfl_xor(s, 16); q += __shfl_xor(q, 16);
            s += __shfl_xor(s, 32); q += __shfl_xor(q, 32);
            if (lane < 16) { rsS[m * 16 + lane][kh] = s; rsQ[m * 16 + lane][kh] = q; }
        }
        __syncthreads();   // (A) zHs, rsS/rsQ, zXs[p] ready

        // ---- gates / state update (thread owns (b, jg)) ----
        float hval;
        {
            float hs = rsS[b][0] + rsS[b][1];
            float hq = rsQ[b][0] + rsQ[b][1];
            float mu = (sxv + hs) * (1.f / 1024.f);
            float var = (sqv + hq) * (1.f / 1024.f) - mu * mu;
            float rs = rsqrtf(var + 1e-5f);

            const float* zx0 = &zXs[p][0][0];
            const float* zx1 = &zXs[p][1][0];
            const float* zh0 = &zHs[0][0];
            const float* zh1 = &zHs[1][0];
            const int i0 = b * 33;
            float zf = zx0[i0 + jl]      + zx1[i0 + jl]      + zh0[i0 + jl]      + zh1[i0 + jl];
            float zi = zx0[i0 + 8 + jl]  + zx1[i0 + 8 + jl]  + zh0[i0 + 8 + jl]  + zh1[i0 + 8 + jl];
            float zg = zx0[i0 + 16 + jl] + zx1[i0 + 16 + jl] + zh0[i0 + 16 + jl] + zh1[i0 + 16 + jl];
            float zo = zx0[i0 + 24 + jl] + zx1[i0 + 24 + jl] + zh0[i0 + 24 + jl] + zh1[i0 + 24 + jl];
            zf = rs * (zf - mu * Scol[jl])      + Ccol[jl];
            zi = rs * (zi - mu * Scol[8 + jl])  + Ccol[8 + jl];
            zg = rs * (zg - mu * Scol[16 + jl]) + Ccol[16 + jl];
            zo = rs * (zo - mu * Scol[24 + jl]) + Ccol[24 + jl];

            float f  = 1.f / (1.f + __expf(-zf));
            float i_ = 1.f / (1.f + __expf(-zi));
            float gg = 2.f / (1.f + __expf(-2.f * zg)) - 1.f;
            float o_ = 1.f / (1.f + __expf(-zo));
            cx = f * cx + i_ * gg;
            float th = 2.f / (1.f + __expf(-2.f * cx)) - 1.f;
            hval = o_ * th + xres;
        }

        // ---- publish into OWN private region + drain + per-wave flag ----
        if (t + 1 < T_STEPS) {
            unsigned hb = (unsigned)f2bf_bits(hval);
            unsigned v01 = hb | ((unsigned)__shfl_xor((int)hb, 1) << 16);
            ull v03 = (ull)v01 |
                ((ull)(unsigned)__shfl_xor((int)v01, 2) << 32);
            if ((jl & 3) == 0) {
                // u64 idx: parity*8192 + g*128 + b*2 + jl/4  (slots {0,1})
                ull* hd = (ull*)hxb + (size_t)(p ^ 1) * 8192
                          + g * 128 + b * 2 + (jl >> 2);
                __hip_atomic_store(hd, v03, __ATOMIC_RELAXED,
                                   __HIP_MEMORY_SCOPE_AGENT);
            }
            asm volatile("s_waitcnt vmcnt(0)" ::: "memory");
            if (lane == 0) {
                __hip_atomic_store(flags + g * 16 + wave, (unsigned)(t + 1),
                                   __ATOMIC_RELAXED, __HIP_MEMORY_SCOPE_AGENT);
            }
        }

        // ---- shadow: out writes ----
        out[(size_t)t * 32768 + b * 512 + jg] = hval;
        if (t == T_STEPS - 1) {
            out[(size_t)T_STEPS * 32768 + b * 512 + jg] = hval;
            out[(size_t)T_STEPS * 32768 + 32768 + b * 512 + jg] = cx;
        }

        __syncthreads();   // (B) zHs/rs*/zXs reuse guard

        // ---- x-GEMM for t+1 from prefetched regs (off critical path) ----
        if (t + 1 < T_STEPS) xgemm_store(afrN, p ^ 1);
    }
}

// ---------------------------------------------------------------------------
extern "C" void kernel_launch(void* const* d_in, const int* in_sizes, int n_in,
                              void* d_out, int out_size, void* d_ws, size_t ws_size,
                              hipStream_t stream)
{
    const float* x    = (const float*)d_in[0];
    const float* ln_g = (const float*)d_in[1];
    const float* ln_b = (const float*)d_in[2];
    const float* Wf   = (const float*)d_in[3];
    const float* bf_  = (const float*)d_in[4];
    const float* Wi   = (const float*)d_in[5];
    const float* bi_  = (const float*)d_in[6];
    const float* Wg   = (const float*)d_in[7];
    const float* bg_  = (const float*)d_in[8];
    const float* Wo   = (const float*)d_in[9];
    const float* bo_  = (const float*)d_in[10];

    char* ws = (char*)d_ws;
    size_t off = 0;
    auto take = [&](size_t bytes) -> char* {
        char* p = ws + off;
        off += (bytes + 255) & ~(size_t)255;
        return p;
    };
    __hip_bfloat16* pack = (__hip_bfloat16*)take((size_t)2097152 * 2); // 4 MB
    float* S             = (float*)take(2048 * 4);
    float* C             = (float*)take(2048 * 4);
    __hip_bfloat16* xb   = (__hip_bfloat16*)take((size_t)33554432 * 2); // 64 MB
    float* sx            = (float*)take(65536 * 4);
    float* sq            = (float*)take(65536 * 4);
    char* ctrl = ws + off;
    unsigned short* hxb  = (unsigned short*)take((size_t)2 * 64 * 512 * 2); // 128 KB
    unsigned int* flags  = (unsigned int*)take(64 * 64);                    // 4 KB
    size_t ctrl_bytes = (size_t)((ws + off) - ctrl);

    hipMemsetAsync(ctrl, 0, ctrl_bytes, stream);
    pack_weights<<<dim3(128), dim3(256), 0, stream>>>(Wf, Wi, Wg, Wo, ln_g, pack);
    compute_sc<<<dim3(8), dim3(256), 0, stream>>>(Wf, Wi, Wg, Wo, bf_, bi_, bg_, bo_,
                                                  ln_g, ln_b, S, C);
    prep_x<<<dim3(16384), dim3(256), 0, stream>>>(x, xb, sx, sq);
    qlstm_main<<<dim3(NWG), dim3(512), 0, stream>>>(x, pack, S, C, xb, sx, sq,
                                                    hxb, flags, (float*)d_out);
}

// Round 16
// 5908.001 us; speedup vs baseline: 2.5347x; 1.0211x over previous
//
#include <hip/hip_runtime.h>
#include <hip/hip_bf16.h>

#define T_STEPS 1024
#define NWG     64

typedef __attribute__((ext_vector_type(8))) short          bf16x8;
typedef __attribute__((ext_vector_type(4))) float          f32x4;
typedef __attribute__((ext_vector_type(8))) unsigned short u16x8;
typedef unsigned long long ull;

static __device__ __forceinline__ unsigned short f2bf_bits(float f) {
    union { __hip_bfloat16 h; unsigned short u; } cv;
    cv.h = __float2bfloat16(f);
    return cv.u;
}

// ---------------------------------------------------------------------------
// P1: fold ln_g into weights, cast bf16, emit in MFMA B-fragment order.
// Chunk layout: [g][part][tn][kstep][lane][e]
//   k  = part*512 + kstep*32 + (lane>>4)*8 + e
//   c  = tn*16 + (lane&15);  n = (c>>3)*512 + g*8 + (c&7)
// ---------------------------------------------------------------------------
__global__ __launch_bounds__(256) void pack_weights(
    const float* __restrict__ Wf, const float* __restrict__ Wi,
    const float* __restrict__ Wg, const float* __restrict__ Wo,
    const float* __restrict__ ln_g, __hip_bfloat16* __restrict__ pack)
{
    __shared__ unsigned short tile[512 * 32];   // [k_local][c]
    const int blk = blockIdx.x;
    const int g = blk >> 1, part = blk & 1;
    const int tid = threadIdx.x;

    for (int idx = tid; idx < 512 * 32; idx += 256) {
        int kl = idx >> 5, c = idx & 31;
        int q = c >> 3, jl = c & 7;
        int k = part * 512 + kl;
        const float* W = (q == 0) ? Wf : ((q == 1) ? Wi : ((q == 2) ? Wg : Wo));
        float v = W[k * 512 + g * 8 + jl] * ln_g[k];
        tile[kl * 32 + c] = f2bf_bits(v);
    }
    __syncthreads();

    unsigned short* out = (unsigned short*)(pack + (size_t)blk * 16384);
    for (int s = tid; s < 2048; s += 256) {        // slot = tn*1024 + ks*64 + l
        int tn = s >> 10, ks = (s >> 6) & 15, l = s & 63;
        u16x8 v;
#pragma unroll
        for (int e = 0; e < 8; ++e) {
            int klocal = ks * 32 + ((l >> 4) * 8) + e;
            int c = tn * 16 + (l & 15);
            v[e] = tile[klocal * 32 + c];
        }
        *(u16x8*)(out + (size_t)s * 8) = v;
    }
}

// ---------------------------------------------------------------------------
// P2: S[n] = sum_k ln_g[k]*W[k,n],  C[n] = sum_k ln_b[k]*W[k,n] + bias[n]
// ---------------------------------------------------------------------------
__global__ __launch_bounds__(256) void compute_sc(
    const float* __restrict__ Wf, const float* __restrict__ Wi,
    const float* __restrict__ Wg, const float* __restrict__ Wo,
    const float* __restrict__ bf_, const float* __restrict__ bi_,
    const float* __restrict__ bg_, const float* __restrict__ bo_,
    const float* __restrict__ ln_g, const float* __restrict__ ln_b,
    float* __restrict__ S, float* __restrict__ C)
{
    int n = blockIdx.x * 256 + threadIdx.x;        // 0..2047
    int q = n >> 9, j = n & 511;
    const float* W = (q == 0) ? Wf : ((q == 1) ? Wi : ((q == 2) ? Wg : Wo));
    const float* bb = (q == 0) ? bf_ : ((q == 1) ? bi_ : ((q == 2) ? bg_ : bo_));
    float accS = 0.f, accC = 0.f;
    for (int k = 0; k < 1024; ++k) {
        float w = W[k * 512 + j];
        accS += ln_g[k] * w;
        accC += ln_b[k] * w;
    }
    S[n] = accS;
    C[n] = accC + bb[j];
}

// ---------------------------------------------------------------------------
// P3: x -> bf16 copy + per-row sum / sumsq (fp32). One wave per (t,b) row.
// ---------------------------------------------------------------------------
__global__ __launch_bounds__(256) void prep_x(
    const float* __restrict__ x, __hip_bfloat16* __restrict__ xb,
    float* __restrict__ sx, float* __restrict__ sq)
{
    const int wave = threadIdx.x >> 6, lane = threadIdx.x & 63;
    const long row = (long)blockIdx.x * 4 + wave;  // 0..65535
    const float* src = x + row * 512 + lane * 8;
    float4 a = *(const float4*)src;
    float4 b = *(const float4*)(src + 4);
    float vals[8] = {a.x, a.y, a.z, a.w, b.x, b.y, b.z, b.w};
    u16x8 o;
    float s = 0.f, qq = 0.f;
#pragma unroll
    for (int e = 0; e < 8; ++e) {
        s += vals[e];
        qq += vals[e] * vals[e];
        o[e] = f2bf_bits(vals[e]);
    }
    *(u16x8*)((unsigned short*)xb + row * 512 + lane * 8) = o;
#pragma unroll
    for (int d = 1; d < 64; d <<= 1) {
        s  += __shfl_xor(s, d);
        qq += __shfl_xor(qq, d);
    }
    if (lane == 0) { sx[row] = s; sq[row] = qq; }
}

// ---------------------------------------------------------------------------
// Main persistent kernel: 64 WGs x 512 threads — R15 structure with:
//  (1) kh-half polling: wave (m,kh) consumes only regions kh*32..kh*32+31,
//      so lane l polls flag-pair of WG kh*32+(l&31) (32 lines, half of R15,
//      and the two halves tolerate mutual skew).
//  (2) parity-double-buffered zHs / rsS / rsQ -> barrier B deleted. Barrier A
//      remains the only per-step barrier (also fences zXs writes of t-1).
// Producer-private h layout (R15): hxb[parity][wg][row 64][8 cols].
// Wave w: m = w>>1 (16-row M tile), kh = w&1 (K half).
// Thread t: b = t>>3, jl = t&7 owns gate/state element (b, 8g+jl).
// ---------------------------------------------------------------------------
__global__ __launch_bounds__(512, 2) void qlstm_main(
    const float* __restrict__ x,
    const __hip_bfloat16* __restrict__ pack,
    const float* __restrict__ Sarr, const float* __restrict__ Carr,
    const __hip_bfloat16* __restrict__ xb,
    const float* __restrict__ sx, const float* __restrict__ sq,
    unsigned short* __restrict__ hxb,   // [2][64 wg][64 row][8] bf16 (zeroed)
    unsigned int* __restrict__ flags,   // [64 WG][16 u32] = 64B/WG (zeroed)
    float* __restrict__ out)            // stacked | hx | cx (fp32)
{
    const int g = blockIdx.x;
    const int tid = threadIdx.x;
    const int wave = tid >> 6, lane = tid & 63;
    const int m = wave >> 1, kh = wave & 1;
    const int b = tid >> 3, jl = tid & 7, jg = g * 8 + jl;

    __shared__ float zXs[2][2][2112];          // [parity][kh][row*33+col]
    __shared__ float zHs[2][2][2112];          // [parity][kh]
    __shared__ float rsS[2][64][2], rsQ[2][64][2];
    __shared__ float Scol[32], Ccol[32];

    if (tid < 32) {
        int n = (tid >> 3) * 512 + g * 8 + (tid & 7);
        Scol[tid] = Sarr[n];
        Ccol[tid] = Carr[n];
    }

    // Persistent B-fragments: 4 x 8 frags x 4 VGPR = 128 regs.
    bf16x8 Bx0[8], Bx1[8], Bh0[8], Bh1[8];
    {
        const bf16x8* px = (const bf16x8*)(pack + (size_t)(g * 2 + 0) * 16384);
        const bf16x8* ph = (const bf16x8*)(pack + (size_t)(g * 2 + 1) * 16384);
#pragma unroll
        for (int i = 0; i < 8; ++i) {
            int ksp = kh * 8 + i;
            Bx0[i] = px[ksp * 64 + lane];
            Bx1[i] = px[1024 + ksp * 64 + lane];
            Bh0[i] = ph[ksp * 64 + lane];
            Bh1[i] = ph[1024 + ksp * 64 + lane];
        }
    }

    const int arow = m * 16 + (lane & 15);
    const int acol = (lane >> 4) * 8;
    const int r0 = m * 16 + (lane >> 4) * 4, c0 = lane & 15;
    float cx = 0.f;

    auto xgemm_store = [&](const bf16x8* af, int par) {
        f32x4 a0 = {0.f, 0.f, 0.f, 0.f}, a1 = {0.f, 0.f, 0.f, 0.f};
#pragma unroll
        for (int ks = 0; ks < 8; ++ks) {
            a0 = __builtin_amdgcn_mfma_f32_16x16x32_bf16(af[ks], Bx0[ks], a0, 0, 0, 0);
            a1 = __builtin_amdgcn_mfma_f32_16x16x32_bf16(af[ks], Bx1[ks], a1, 0, 0, 0);
        }
        float* zb = &zXs[par][kh][0];
#pragma unroll
        for (int r = 0; r < 4; ++r) {
            zb[(r0 + r) * 33 + c0]      = a0[r];
            zb[(r0 + r) * 33 + 16 + c0] = a1[r];
        }
    };

    // zX for t=0 (recurrence-independent)
    {
        const bf16x8* Ap = (const bf16x8*)(xb + (size_t)arow * 512 + kh * 256 + acol);
        bf16x8 af[8];
#pragma unroll
        for (int ks = 0; ks < 8; ++ks) af[ks] = Ap[ks * 4];
        xgemm_store(af, 0);
    }

    for (int t = 0; t < T_STEPS; ++t) {
        const int p = t & 1;

        // ---- recurrence-independent loads issued BEFORE the spin ----
        float xres = x[(size_t)t * 32768 + b * 512 + jg];
        float sxv = sx[t * 64 + b];
        float sqv = sq[t * 64 + b];
        bf16x8 afrN[8];                     // x A-frags for t+1
        if (t + 1 < T_STEPS) {
            const bf16x8* Ap = (const bf16x8*)(xb + (size_t)(t + 1) * 32768
                                               + arow * 512 + kh * 256 + acol);
#pragma unroll
            for (int ks = 0; ks < 8; ++ks) afrN[ks] = Ap[ks * 4];
        }

        // ---- spin: lane l polls waves {2m,2m+1} of WG kh*32+(l&31) ----
        if (t) {
            const ull* fp_ = (const ull*)(flags + (kh * 32 + (lane & 31)) * 16 + m * 2);
            int slp = 0;
            for (;;) {
                ull v = __hip_atomic_load(fp_, __ATOMIC_RELAXED,
                                          __HIP_MEMORY_SCOPE_AGENT);
                unsigned fa = (unsigned)v, fb = (unsigned)(v >> 32);
                unsigned mn = fa < fb ? fa : fb;
                if (__all((int)mn >= t)) break;
                if      (slp == 0) __builtin_amdgcn_s_sleep(1);
                else if (slp == 1) __builtin_amdgcn_s_sleep(2);
                else if (slp == 2) __builtin_amdgcn_s_sleep(4);
                else               __builtin_amdgcn_s_sleep(8);
                if (slp < 3) ++slp;
            }
            asm volatile("" ::: "memory");
        }

        // ---- coherent h A-frag loads from producer-private regions ----
        ull hlo[8], hhi[8];
        {
            const ull* hp = (const ull*)hxb + (size_t)p * 8192;
            const int g0 = kh * 32 + (lane >> 4);
            const int rb = arow * 2;
#pragma unroll
            for (int ks = 0; ks < 8; ++ks) {
                const int idx = (g0 + ks * 4) * 128 + rb;
                hlo[ks] = __hip_atomic_load(hp + idx, __ATOMIC_RELAXED,
                                            __HIP_MEMORY_SCOPE_AGENT);
                hhi[ks] = __hip_atomic_load(hp + idx + 1, __ATOMIC_RELAXED,
                                            __HIP_MEMORY_SCOPE_AGENT);
            }
        }

        // ---- h-GEMM (critical path) ----
        {
            f32x4 h0 = {0.f, 0.f, 0.f, 0.f}, h1 = {0.f, 0.f, 0.f, 0.f};
#pragma unroll
            for (int ks = 0; ks < 8; ++ks) {
                union { ull u[2]; bf16x8 v; } cv;
                cv.u[0] = hlo[ks]; cv.u[1] = hhi[ks];
                h0 = __builtin_amdgcn_mfma_f32_16x16x32_bf16(cv.v, Bh0[ks], h0, 0, 0, 0);
                h1 = __builtin_amdgcn_mfma_f32_16x16x32_bf16(cv.v, Bh1[ks], h1, 0, 0, 0);
            }
            float* zb = &zHs[p][kh][0];
#pragma unroll
            for (int r = 0; r < 4; ++r) {
                zb[(r0 + r) * 33 + c0]      = h0[r];
                zb[(r0 + r) * 33 + 16 + c0] = h1[r];
            }
        }

        // ---- local LN stats from the loaded h words ----
        {
            float s = 0.f, q = 0.f;
#pragma unroll
            for (int ks = 0; ks < 8; ++ks) {
                unsigned uu[4] = { (unsigned)hlo[ks], (unsigned)(hlo[ks] >> 32),
                                   (unsigned)hhi[ks], (unsigned)(hhi[ks] >> 32) };
#pragma unroll
                for (int j = 0; j < 4; ++j) {
                    float f0 = __uint_as_float(uu[j] << 16);
                    float f1 = __uint_as_float(uu[j] & 0xffff0000u);
                    s += f0 + f1;
                    q = fmaf(f0, f0, fmaf(f1, f1, q));
                }
            }
            // lanes {l, l^16, l^32, l^48} share arow
            s += __shfl_xor(s, 16); q += __shfl_xor(q, 16);
            s += __shfl_xor(s, 32); q += __shfl_xor(q, 32);
            if (lane < 16) {
                rsS[p][m * 16 + lane][kh] = s;
                rsQ[p][m * 16 + lane][kh] = q;
            }
        }
        __syncthreads();   // (A) the ONLY per-step barrier

        // ---- gates / state update (thread owns (b, jg)) ----
        float hval;
        {
            float hs = rsS[p][b][0] + rsS[p][b][1];
            float hq = rsQ[p][b][0] + rsQ[p][b][1];
            float mu = (sxv + hs) * (1.f / 1024.f);
            float var = (sqv + hq) * (1.f / 1024.f) - mu * mu;
            float rs = rsqrtf(var + 1e-5f);

            const float* zx0 = &zXs[p][0][0];
            const float* zx1 = &zXs[p][1][0];
            const float* zh0 = &zHs[p][0][0];
            const float* zh1 = &zHs[p][1][0];
            const int i0 = b * 33;
            float zf = zx0[i0 + jl]      + zx1[i0 + jl]      + zh0[i0 + jl]      + zh1[i0 + jl];
            float zi = zx0[i0 + 8 + jl]  + zx1[i0 + 8 + jl]  + zh0[i0 + 8 + jl]  + zh1[i0 + 8 + jl];
            float zg = zx0[i0 + 16 + jl] + zx1[i0 + 16 + jl] + zh0[i0 + 16 + jl] + zh1[i0 + 16 + jl];
            float zo = zx0[i0 + 24 + jl] + zx1[i0 + 24 + jl] + zh0[i0 + 24 + jl] + zh1[i0 + 24 + jl];
            zf = rs * (zf - mu * Scol[jl])      + Ccol[jl];
            zi = rs * (zi - mu * Scol[8 + jl])  + Ccol[8 + jl];
            zg = rs * (zg - mu * Scol[16 + jl]) + Ccol[16 + jl];
            zo = rs * (zo - mu * Scol[24 + jl]) + Ccol[24 + jl];

            float f  = 1.f / (1.f + __expf(-zf));
            float i_ = 1.f / (1.f + __expf(-zi));
            float gg = 2.f / (1.f + __expf(-2.f * zg)) - 1.f;
            float o_ = 1.f / (1.f + __expf(-zo));
            cx = f * cx + i_ * gg;
            float th = 2.f / (1.f + __expf(-2.f * cx)) - 1.f;
            hval = o_ * th + xres;
        }

        // ---- publish into OWN private region + drain + per-wave flag ----
        if (t + 1 < T_STEPS) {
            unsigned hb = (unsigned)f2bf_bits(hval);
            unsigned v01 = hb | ((unsigned)__shfl_xor((int)hb, 1) << 16);
            ull v03 = (ull)v01 |
                ((ull)(unsigned)__shfl_xor((int)v01, 2) << 32);
            if ((jl & 3) == 0) {
                // u64 idx: parity*8192 + g*128 + b*2 + jl/4  (slots {0,1})
                ull* hd = (ull*)hxb + (size_t)(p ^ 1) * 8192
                          + g * 128 + b * 2 + (jl >> 2);
                __hip_atomic_store(hd, v03, __ATOMIC_RELAXED,
                                   __HIP_MEMORY_SCOPE_AGENT);
            }
            asm volatile("s_waitcnt vmcnt(0)" ::: "memory");
            if (lane == 0) {
                __hip_atomic_store(flags + g * 16 + wave, (unsigned)(t + 1),
                                   __ATOMIC_RELAXED, __HIP_MEMORY_SCOPE_AGENT);
            }
        }

        // ---- shadow: out writes (post-flag, off critical path) ----
        out[(size_t)t * 32768 + b * 512 + jg] = hval;
        if (t == T_STEPS - 1) {
            out[(size_t)T_STEPS * 32768 + b * 512 + jg] = hval;
            out[(size_t)T_STEPS * 32768 + 32768 + b * 512 + jg] = cx;
        }

        // ---- x-GEMM for t+1 from prefetched regs (off critical path) ----
        if (t + 1 < T_STEPS) xgemm_store(afrN, p ^ 1);
    }
}

// ---------------------------------------------------------------------------
extern "C" void kernel_launch(void* const* d_in, const int* in_sizes, int n_in,
                              void* d_out, int out_size, void* d_ws, size_t ws_size,
                              hipStream_t stream)
{
    const float* x    = (const float*)d_in[0];
    const float* ln_g = (const float*)d_in[1];
    const float* ln_b = (const float*)d_in[2];
    const float* Wf   = (const float*)d_in[3];
    const float* bf_  = (const float*)d_in[4];
    const float* Wi   = (const float*)d_in[5];
    const float* bi_  = (const float*)d_in[6];
    const float* Wg   = (const float*)d_in[7];
    const float* bg_  = (const float*)d_in[8];
    const float* Wo   = (const float*)d_in[9];
    const float* bo_  = (const float*)d_in[10];

    char* ws = (char*)d_ws;
    size_t off = 0;
    auto take = [&](size_t bytes) -> char* {
        char* p = ws + off;
        off += (bytes + 255) & ~(size_t)255;
        return p;
    };
    __hip_bfloat16* pack = (__hip_bfloat16*)take((size_t)2097152 * 2); // 4 MB
    float* S             = (float*)take(2048 * 4);
    float* C             = (float*)take(2048 * 4);
    __hip_bfloat16* xb   = (__hip_bfloat16*)take((size_t)33554432 * 2); // 64 MB
    float* sx            = (float*)take(65536 * 4);
    float* sq            = (float*)take(65536 * 4);
    char* ctrl = ws + off;
    unsigned short* hxb  = (unsigned short*)take((size_t)2 * 64 * 512 * 2); // 128 KB
    unsigned int* flags  = (unsigned int*)take(64 * 64);                    // 4 KB
    size_t ctrl_bytes = (size_t)((ws + off) - ctrl);

    hipMemsetAsync(ctrl, 0, ctrl_bytes, stream);
    pack_weights<<<dim3(128), dim3(256), 0, stream>>>(Wf, Wi, Wg, Wo, ln_g, pack);
    compute_sc<<<dim3(8), dim3(256), 0, stream>>>(Wf, Wi, Wg, Wo, bf_, bi_, bg_, bo_,
                                                  ln_g, ln_b, S, C);
    prep_x<<<dim3(16384), dim3(256), 0, stream>>>(x, xb, sx, sq);
    qlstm_main<<<dim3(NWG), dim3(512), 0, stream>>>(x, pack, S, C, xb, sx, sq,
                                                    hxb, flags, (float*)d_out);
}